// Round 3
// baseline (26455.795 us; speedup 1.0000x reference)
//
#include <hip/hip_runtime.h>
#include <math.h>

#define EOS_ID 2
#define START_ID 1
#define NEGV (-1e9f)

__device__ __forceinline__ float sigmoidf_(float x) { return 1.f / (1.f + expf(-x)); }

// merge two desc-sorted (val, col) top-4 lists; tie: lower col wins. Result into l*.
__device__ __forceinline__ void merge4_(float lv[4], int lc[4],
                                        const float rv[4], const int rc[4]) {
    float ov[4]; int oc[4];
    int ai = 0, bi = 0;
    #pragma unroll
    for (int o = 0; o < 4; o++) {
        const float avv = (ai == 0) ? lv[0] : (ai == 1) ? lv[1] : (ai == 2) ? lv[2] : lv[3];
        const int   acc = (ai == 0) ? lc[0] : (ai == 1) ? lc[1] : (ai == 2) ? lc[2] : lc[3];
        const float bvv = (bi == 0) ? rv[0] : (bi == 1) ? rv[1] : (bi == 2) ? rv[2] : rv[3];
        const int   bcc = (bi == 0) ? rc[0] : (bi == 1) ? rc[1] : (bi == 2) ? rc[2] : rc[3];
        const bool ta = (avv > bvv) || (avv == bvv && acc < bcc);
        ov[o] = ta ? avv : bvv;
        oc[o] = ta ? acc : bcc;
        if (ta) ai++; else bi++;
    }
    #pragma unroll
    for (int o = 0; o < 4; o++) { lv[o] = ov[o]; lc[o] = oc[o]; }
}

__device__ __forceinline__ void lse_combine_(float& m, float& s, float m2, float s2) {
    const float M = fmaxf(m, m2);
    s = s * expf(m - M) + s2 * expf(m2 - M);
    m = M;
}

// ---------------------------------------------------------------------------
// Software grid barrier (device-scope). bar[0]=arrival count, bar[1]=generation.
// Requires all nb blocks co-resident (guaranteed by launch_bounds + grid size).
// Release: __threadfence (L2 writeback) before arrival. Spin: RELAXED agent
// atomic loads (read through coherence point, no cache-invalidate thrash).
// Acquire: one __threadfence after the flag flips. Timeout valve prevents hangs.
// ---------------------------------------------------------------------------
__device__ __forceinline__ void gsync_(int* bar, int nb, int& g, bool& dead) {
    __syncthreads();
    if (threadIdx.x == 0 && !dead) {
        __threadfence();
        if (atomicAdd(&bar[0], 1) == nb - 1) {
            atomicExch(&bar[0], 0);
            __hip_atomic_store(&bar[1], g + 1, __ATOMIC_RELEASE, __HIP_MEMORY_SCOPE_AGENT);
        } else {
            int sp = 0;
            while (__hip_atomic_load(&bar[1], __ATOMIC_RELAXED, __HIP_MEMORY_SCOPE_AGENT) - g <= 0) {
                if (++sp > (1 << 22)) { dead = true; break; }
            }
            __threadfence();
        }
        g++;
    }
    __syncthreads();
}

// ---------------------------------------------------------------------------
// Generic fp32 GEMM (reg-staged prefetch). Used for Xz (AMODE 2) and keysT
// (TRANS 1) only — both wide one-shot launches.
// ---------------------------------------------------------------------------
template<int BM, int BN, int BK, int AMODE, int TRANS>
__global__ void __launch_bounds__(256) gemm_k(
    const float* __restrict__ A, const float* __restrict__ B,
    const float* __restrict__ bias, float* __restrict__ C,
    int M, int N, int K, const int* __restrict__ tokp)
{
    static_assert(BN == 64, "");
    constexpr int TM = BM / 16, TN = BN / 16;
    __shared__ __align__(16) float As[BK][BM];
    __shared__ __align__(16) float Bs[BK][BN];
    const int tid = threadIdx.x;
    const int n0 = blockIdx.x * BN, m0 = blockIdx.y * BM;
    const int tx = tid & 15, ty = tid >> 4;
    (void)M;

    float acc[TM][TN];
    #pragma unroll
    for (int i = 0; i < TM; i++)
        #pragma unroll
        for (int j = 0; j < TN; j++) acc[i][j] = 0.f;

    constexpr int A4 = BM * BK / 4;
    const bool aP = (A4 >= 256) || (tid < A4);
    const int am = tid / (BK / 4), ak4 = tid % (BK / 4);
    const int bk = tid >> 4, bn4 = tid & 15;

    const float* aRow = nullptr;
    if (aP) {
        if (AMODE == 0) {
            aRow = A + (size_t)(m0 + am) * K;
        } else {  // AMODE 2: gather embedding row once
            const int r = m0 + am;
            const int s = r >> 5, bidx = r & 31;
            aRow = A + (size_t)tokp[bidx * 128 + s] * 512;
        }
    }

    float4 aPF{}, bPF;
    if (aP) aPF = *reinterpret_cast<const float4*>(aRow + ak4 * 4);
    bPF = *reinterpret_cast<const float4*>(B + (size_t)bk * N + n0 + bn4 * 4);

    for (int k0 = 0; k0 < K; k0 += BK) {
        if (aP) {
            As[ak4 * 4 + 0][am] = aPF.x;
            As[ak4 * 4 + 1][am] = aPF.y;
            As[ak4 * 4 + 2][am] = aPF.z;
            As[ak4 * 4 + 3][am] = aPF.w;
        }
        *reinterpret_cast<float4*>(&Bs[bk][bn4 * 4]) = bPF;
        __syncthreads();
        const int kn = k0 + BK;
        if (kn < K) {
            if (aP) aPF = *reinterpret_cast<const float4*>(aRow + kn + ak4 * 4);
            bPF = *reinterpret_cast<const float4*>(B + (size_t)(kn + bk) * N + n0 + bn4 * 4);
        }
        #pragma unroll
        for (int kk = 0; kk < BK; kk++) {
            float af[TM], bf[TN];
            if constexpr (TM == 4) {
                const float4 t4 = *reinterpret_cast<const float4*>(&As[kk][ty * TM]);
                af[0] = t4.x; af[1] = t4.y; af[2] = t4.z; af[3] = t4.w;
            } else if constexpr (TM == 2) {
                const float2 t2 = *reinterpret_cast<const float2*>(&As[kk][ty * TM]);
                af[0] = t2.x; af[1] = t2.y;
            } else {
                af[0] = As[kk][ty];
            }
            const float4 b4 = *reinterpret_cast<const float4*>(&Bs[kk][tx * TN]);
            bf[0] = b4.x; bf[1] = b4.y; bf[2] = b4.z; bf[3] = b4.w;
            #pragma unroll
            for (int i = 0; i < TM; i++)
                #pragma unroll
                for (int j = 0; j < TN; j++) acc[i][j] += af[i] * bf[j];
        }
        __syncthreads();
    }

    if constexpr (TRANS) {
        #pragma unroll
        for (int i = 0; i < TM; i++) {
            const int r = m0 + ty * TM + i;
            const int b = r >> 7, s = r & 127;
            #pragma unroll
            for (int j = 0; j < TN; j++)
                C[((size_t)b * 512 + (n0 + tx * TN + j)) * 128 + s] = acc[i][j];
        }
    } else {
        float bv[TN];
        #pragma unroll
        for (int j = 0; j < TN; j++) bv[j] = bias ? bias[n0 + tx * TN + j] : 0.f;
        #pragma unroll
        for (int i = 0; i < TM; i++) {
            float4 o;
            o.x = acc[i][0] + bv[0]; o.y = acc[i][1] + bv[1];
            o.z = acc[i][2] + bv[2]; o.w = acc[i][3] + bv[3];
            *reinterpret_cast<float4*>(C + (size_t)(m0 + ty * TM + i) * N + n0 + tx * TN) = o;
        }
    }
}

// ---------------------------------------------------------------------------
// One-time pack + zero-init of enc_c/hzero + zero the two barrier states.
// ---------------------------------------------------------------------------
__global__ void __launch_bounds__(256) pack_dec_k(
    const float* __restrict__ W_dec, const float* __restrict__ U_dec,
    const float* __restrict__ b_dec, float* __restrict__ Bp, float* __restrict__ bp,
    float* __restrict__ enc_c, float* __restrict__ hzero,
    int* __restrict__ barA, int* __restrict__ barB)
{
    const int idx = blockIdx.x * 256 + threadIdx.x;
    if (idx < 1536 * 2048) {
        const int k = idx >> 11, cp = idx & 2047;
        const int j = cp >> 2, g = cp & 3;
        const int sc = g * 512 + j;
        Bp[idx] = (k < 1024) ? W_dec[(size_t)k * 2048 + sc]
                             : U_dec[(size_t)(k - 1024) * 2048 + sc];
        if (idx < 2048) bp[idx] = b_dec[sc];
    }
    if (idx < 32 * 512) enc_c[idx] = 0.f;
    if (idx < 512) hzero[idx] = 0.f;
    if (idx == 0) { barA[0] = 0; barA[1] = 0; barB[0] = 0; barB[1] = 0; }
}

// ---------------------------------------------------------------------------
// Persistent encoder LSTM: 128 steps, software grid barrier.
// Grid 128 blocks (16 jt x 8 bgroups of 4 batches), block 256.
// ---------------------------------------------------------------------------
__global__ void __launch_bounds__(256, 1) enc_persist_k(
    const float* __restrict__ Xz, const float* __restrict__ hzero,
    const float* __restrict__ U, float* __restrict__ c,
    float* __restrict__ enc_out, int* __restrict__ bar)
{
    __shared__ __align__(16) float hs[512][4];
    __shared__ __align__(16) float zp[8][4][128];
    __shared__ float zfin[4][32][4];
    const int tid = threadIdx.x;
    const int jt = blockIdx.x & 15;          // 16 jtiles x 32 j-values
    const int b0 = (blockIdx.x >> 4) * 4;    // 8 bgroups x 4 batches
    int gen = 0; bool dead = false;

    for (int t = 0; t < 128; t++) {
        const float* hprev = t ? (enc_out + (size_t)(t - 1) * 512) : hzero;
        const long hstride = t ? (long)(128 * 512) : 0;

        #pragma unroll
        for (int i2 = 0; i2 < 2; i2++) {
            const int idx = tid + i2 * 256;
            const int bb = idx >> 7, k4 = idx & 127;
            const float4 hv = *reinterpret_cast<const float4*>(
                hprev + (size_t)(b0 + bb) * hstride + k4 * 4);
            hs[k4 * 4 + 0][bb] = hv.x; hs[k4 * 4 + 1][bb] = hv.y;
            hs[k4 * 4 + 2][bb] = hv.z; hs[k4 * 4 + 3][bb] = hv.w;
        }
        __syncthreads();

        {
            const int kp = tid >> 5, cq = tid & 31;
            const int g = cq >> 3, j4 = (cq & 7) * 4;
            const int col = g * 512 + jt * 32 + j4;
            const int kbase = kp * 64;
            float4 A0 = {0.f,0.f,0.f,0.f}, A1 = {0.f,0.f,0.f,0.f};
            float4 A2 = {0.f,0.f,0.f,0.f}, A3 = {0.f,0.f,0.f,0.f};
            #pragma unroll 8
            for (int k = 0; k < 64; k++) {
                const float4 u4 = *reinterpret_cast<const float4*>(
                    U + (size_t)(kbase + k) * 2048 + col);
                const float4 h4 = *reinterpret_cast<const float4*>(&hs[kbase + k][0]);
                A0.x += h4.x * u4.x; A0.y += h4.x * u4.y; A0.z += h4.x * u4.z; A0.w += h4.x * u4.w;
                A1.x += h4.y * u4.x; A1.y += h4.y * u4.y; A1.z += h4.y * u4.z; A1.w += h4.y * u4.w;
                A2.x += h4.z * u4.x; A2.y += h4.z * u4.y; A2.z += h4.z * u4.z; A2.w += h4.z * u4.w;
                A3.x += h4.w * u4.x; A3.y += h4.w * u4.y; A3.z += h4.w * u4.z; A3.w += h4.w * u4.w;
            }
            *reinterpret_cast<float4*>(&zp[kp][0][g * 32 + j4]) = A0;
            *reinterpret_cast<float4*>(&zp[kp][1][g * 32 + j4]) = A1;
            *reinterpret_cast<float4*>(&zp[kp][2][g * 32 + j4]) = A2;
            *reinterpret_cast<float4*>(&zp[kp][3][g * 32 + j4]) = A3;
        }
        __syncthreads();

        #pragma unroll
        for (int i2 = 0; i2 < 2; i2++) {
            const int idx = tid + i2 * 256;
            const int bb = idx >> 7, rem = idx & 127;
            const int jj = rem >> 2, gg2 = rem & 3;
            float s = 0.f;
            #pragma unroll
            for (int p = 0; p < 8; p++) s += zp[p][bb][gg2 * 32 + jj];
            s += Xz[(size_t)t * 32 * 2048 + (size_t)(b0 + bb) * 2048 + gg2 * 512 + jt * 32 + jj];
            zfin[bb][jj][gg2] = s;
        }
        __syncthreads();

        if (tid < 128) {
            const int bb = tid >> 5, jj = tid & 31;
            const int b = b0 + bb;
            const float iv = sigmoidf_(zfin[bb][jj][0]);
            const float fv = sigmoidf_(zfin[bb][jj][1]);
            const float gv = tanhf(zfin[bb][jj][2]);
            const float ov = sigmoidf_(zfin[bb][jj][3]);
            const int jglob = jt * 32 + jj;
            const size_t ci = (size_t)b * 512 + jglob;
            const float cv = fv * c[ci] + iv * gv;
            c[ci] = cv;
            enc_out[(size_t)b * 128 * 512 + (size_t)t * 512 + jglob] = ov * tanhf(cv);
        }
        gsync_(bar, 128, gen, dead);
    }
}

// ---------------------------------------------------------------------------
// Decoder init
// ---------------------------------------------------------------------------
__global__ void __launch_bounds__(256) init_dec_k(
    const float* __restrict__ enc_out, const float* __restrict__ enc_c,
    float* __restrict__ h_buf, float* __restrict__ c_buf, float* __restrict__ attn_buf,
    float* __restrict__ cum, int* __restrict__ fin, int* __restrict__ tok)
{
    const int idx = blockIdx.x * 256 + threadIdx.x;
    const int r = idx >> 9, jcol = idx & 511;
    const int b = r >> 2, kbeam = r & 3;
    h_buf[idx] = enc_out[((size_t)b * 128 + 127) * 512 + jcol];
    c_buf[idx] = enc_c[(size_t)b * 512 + jcol];
    attn_buf[idx] = 0.f;
    if (jcol == 0) {
        cum[r] = (kbeam == 0) ? 0.f : NEGV;
        fin[r] = 0;
        tok[r] = START_ID;
    }
}

// ---------------------------------------------------------------------------
// Persistent decoder: 48 steps x 6 phases, software grid barrier.
// Grid 512 blocks, block 256, __launch_bounds__(256,2) -> 2 blocks/CU
// guaranteed co-residency (512 = capacity). LDS = 12.3KB union.
// Phase bodies are verbatim ports of the round-1-verified kernels.
// ---------------------------------------------------------------------------
struct __align__(16) SDec {
    union {
        struct { float As[16][16];  float Bs[16][64]; } g;   // zgemm & attnGEMM
        struct { float q[512]; float scp[2][128]; float sc[128]; float red[128]; } a;
        struct { float As[16][128]; float Bs[16][64]; } l;   // logits
        struct { float sm[256]; float ss[256]; float sv[256][4]; int sci[256][4]; } m;
    } u;
    int par[4];
};

#define NB_DEC 512

__global__ void __launch_bounds__(256, 2) dec_persist_k(
    const float* __restrict__ dec_emb, const float* __restrict__ Bp,
    const float* __restrict__ bp, int* __restrict__ tok,
    float* __restrict__ attn_buf, float* __restrict__ h_buf,
    float* __restrict__ c_buf, float* __restrict__ c_new,
    float* __restrict__ Acat, const float* __restrict__ keysT,
    const float* __restrict__ enc_out, const float* __restrict__ W_attn,
    float* __restrict__ attn_new, const float* __restrict__ W_out,
    const float* __restrict__ b_out, float* __restrict__ pmax,
    float* __restrict__ psum, float* __restrict__ pval, int* __restrict__ pcol,
    float* __restrict__ cum, int* __restrict__ fin,
    int* __restrict__ parents, int* __restrict__ toks,
    float* __restrict__ rowlse_g, float* __restrict__ rowv_g, int* __restrict__ rowc_g,
    int* __restrict__ bar)
{
    __shared__ SDec S;
    const int tid = threadIdx.x;
    const int bid = blockIdx.x;
    const int tx = tid & 15, ty = tid >> 4;
    int gen = 0; bool dead = false;

    for (int step = 0; step < 48; step++) {
        // ---------------- phase 1: zgemm + LSTM gates (256 blocks) ----------
        if (bid < 256) {
            const int n0 = (bid & 31) * 64, m0 = (bid >> 5) * 16;
            float acc[4] = {0.f, 0.f, 0.f, 0.f};
            const bool aP = tid < 64;
            const int am = tid >> 2, ak4 = tid & 3;
            const int r = m0 + am;
            const int bk = tid >> 4, bn4 = tid & 15;
            const float* embRow = nullptr;
            if (aP) {
                int tk = tok[r];
                tk = (tk < 0) ? 0 : ((tk > 31999) ? 31999 : tk);  // safety clamp
                embRow = dec_emb + (size_t)tk * 512;
            }

            auto loadA = [&](int k0) -> float4 {
                const int kg = k0 + ak4 * 4;
                if (kg < 512)
                    return *reinterpret_cast<const float4*>(embRow + kg);
                if (kg < 1024)
                    return *reinterpret_cast<const float4*>(attn_buf + (size_t)r * 512 + (kg - 512));
                return *reinterpret_cast<const float4*>(h_buf + (size_t)r * 512 + (kg - 1024));
            };

            float4 aPF{}, bPF;
            if (aP) aPF = loadA(0);
            bPF = *reinterpret_cast<const float4*>(Bp + (size_t)bk * 2048 + n0 + bn4 * 4);

            for (int k0 = 0; k0 < 1536; k0 += 16) {
                if (aP) {
                    S.u.g.As[ak4 * 4 + 0][am] = aPF.x;
                    S.u.g.As[ak4 * 4 + 1][am] = aPF.y;
                    S.u.g.As[ak4 * 4 + 2][am] = aPF.z;
                    S.u.g.As[ak4 * 4 + 3][am] = aPF.w;
                }
                *reinterpret_cast<float4*>(&S.u.g.Bs[bk][bn4 * 4]) = bPF;
                __syncthreads();
                const int kn = k0 + 16;
                if (kn < 1536) {
                    if (aP) aPF = loadA(kn);
                    bPF = *reinterpret_cast<const float4*>(Bp + (size_t)(kn + bk) * 2048 + n0 + bn4 * 4);
                }
                #pragma unroll
                for (int kk = 0; kk < 16; kk++) {
                    const float a = S.u.g.As[kk][ty];
                    const float4 b4 = *reinterpret_cast<const float4*>(&S.u.g.Bs[kk][tx * 4]);
                    acc[0] += a * b4.x; acc[1] += a * b4.y;
                    acc[2] += a * b4.z; acc[3] += a * b4.w;
                }
                __syncthreads();
            }

            const int rr = m0 + ty;
            const int j = (n0 >> 2) + tx;
            const float iv = sigmoidf_(acc[0] + bp[n0 + tx * 4 + 0]);
            const float fv = sigmoidf_(acc[1] + bp[n0 + tx * 4 + 1]);
            const float gv = tanhf   (acc[2] + bp[n0 + tx * 4 + 2]);
            const float ov = sigmoidf_(acc[3] + bp[n0 + tx * 4 + 3]);
            const float cv = fv * c_buf[(size_t)rr * 512 + j] + iv * gv;
            c_new[(size_t)rr * 512 + j] = cv;
            Acat[(size_t)rr * 1024 + j] = ov * tanhf(cv);
        }
        gsync_(bar, NB_DEC, gen, dead);

        // ---------------- phase 2: attention (128 blocks) -------------------
        if (bid < 128) {
            const int r = bid;
            const int b = r >> 2;

            if (tid < 128)
                reinterpret_cast<float4*>(S.u.a.q)[tid] =
                    reinterpret_cast<const float4*>(Acat + (size_t)r * 1024)[tid];
            __syncthreads();

            {
                const int half = tid >> 7, s = tid & 127;
                const float* kp = keysT + ((size_t)b * 512 + half * 256) * 128 + s;
                float acc = 0.f;
                #pragma unroll 8
                for (int kk = 0; kk < 256; kk++)
                    acc += S.u.a.q[half * 256 + kk] * kp[(size_t)kk * 128];
                S.u.a.scp[half][s] = acc;
            }
            __syncthreads();
            if (tid < 128) S.u.a.sc[tid] = S.u.a.scp[0][tid] + S.u.a.scp[1][tid];
            __syncthreads();
            if (tid < 64) S.u.a.red[tid] = fmaxf(S.u.a.sc[tid], S.u.a.sc[tid + 64]);
            __syncthreads();
            for (int st = 32; st >= 1; st >>= 1) {
                if (tid < st) S.u.a.red[tid] = fmaxf(S.u.a.red[tid], S.u.a.red[tid + st]);
                __syncthreads();
            }
            const float m = S.u.a.red[0];
            __syncthreads();
            if (tid < 128) S.u.a.sc[tid] = expf(S.u.a.sc[tid] - m);
            __syncthreads();
            if (tid < 64) S.u.a.red[tid] = S.u.a.sc[tid] + S.u.a.sc[tid + 64];
            __syncthreads();
            for (int st = 32; st >= 1; st >>= 1) {
                if (tid < st) S.u.a.red[tid] += S.u.a.red[tid + st];
                __syncthreads();
            }
            const float Ssum = S.u.a.red[0];
            __syncthreads();
            if (tid < 128) S.u.a.sc[tid] = S.u.a.sc[tid] / Ssum;
            __syncthreads();

            float a0 = 0.f, a1 = 0.f;
            for (int s = 0; s < 128; s++) {
                const float w = S.u.a.sc[s];
                const float* vr = enc_out + ((size_t)b * 128 + s) * 512;
                a0 += w * vr[tid];
                a1 += w * vr[tid + 256];
            }
            Acat[(size_t)r * 1024 + 512 + tid] = a0;
            Acat[(size_t)r * 1024 + 512 + tid + 256] = a1;
        }
        gsync_(bar, NB_DEC, gen, dead);

        // ---------------- phase 3: attn_new = Acat @ W_attn (64 blocks) -----
        if (bid < 64) {
            const int n0 = (bid & 7) * 64, m0 = (bid >> 3) * 16;
            float acc[4] = {0.f, 0.f, 0.f, 0.f};
            const bool aP = tid < 64;
            const int am = tid >> 2, ak4 = tid & 3;
            const int bk = tid >> 4, bn4 = tid & 15;
            const float* aRow = Acat + (size_t)(m0 + am) * 1024;

            float4 aPF{}, bPF;
            if (aP) aPF = *reinterpret_cast<const float4*>(aRow + ak4 * 4);
            bPF = *reinterpret_cast<const float4*>(W_attn + (size_t)bk * 512 + n0 + bn4 * 4);

            for (int k0 = 0; k0 < 1024; k0 += 16) {
                if (aP) {
                    S.u.g.As[ak4 * 4 + 0][am] = aPF.x;
                    S.u.g.As[ak4 * 4 + 1][am] = aPF.y;
                    S.u.g.As[ak4 * 4 + 2][am] = aPF.z;
                    S.u.g.As[ak4 * 4 + 3][am] = aPF.w;
                }
                *reinterpret_cast<float4*>(&S.u.g.Bs[bk][bn4 * 4]) = bPF;
                __syncthreads();
                const int kn = k0 + 16;
                if (kn < 1024) {
                    if (aP) aPF = *reinterpret_cast<const float4*>(aRow + kn + ak4 * 4);
                    bPF = *reinterpret_cast<const float4*>(W_attn + (size_t)(kn + bk) * 512 + n0 + bn4 * 4);
                }
                #pragma unroll
                for (int kk = 0; kk < 16; kk++) {
                    const float a = S.u.g.As[kk][ty];
                    const float4 b4 = *reinterpret_cast<const float4*>(&S.u.g.Bs[kk][tx * 4]);
                    acc[0] += a * b4.x; acc[1] += a * b4.y;
                    acc[2] += a * b4.z; acc[3] += a * b4.w;
                }
                __syncthreads();
            }
            float4 o;
            o.x = acc[0]; o.y = acc[1]; o.z = acc[2]; o.w = acc[3];
            *reinterpret_cast<float4*>(attn_new + (size_t)(m0 + ty) * 512 + n0 + tx * 4) = o;
        }
        gsync_(bar, NB_DEC, gen, dead);

        // ---------------- phase 4: logits + fused top-4 partials (500 blocks)
        if (bid < 500) {
            const int tile = bid;
            const int n0 = tile * 64;
            float acc[8][4];
            #pragma unroll
            for (int i = 0; i < 8; i++)
                #pragma unroll
                for (int j = 0; j < 4; j++) acc[i][j] = 0.f;

            const int amA = tid >> 2, ak4 = tid & 3;
            const int bkB = tid >> 4, bn4 = tid & 15;

            float4 aPF0 = *reinterpret_cast<const float4*>(attn_new + (size_t)amA * 512 + ak4 * 4);
            float4 aPF1 = *reinterpret_cast<const float4*>(attn_new + (size_t)(64 + amA) * 512 + ak4 * 4);
            float4 bPF  = *reinterpret_cast<const float4*>(W_out + (size_t)bkB * 32000 + n0 + bn4 * 4);

            for (int k0 = 0; k0 < 512; k0 += 16) {
                S.u.l.As[ak4 * 4 + 0][amA] = aPF0.x;
                S.u.l.As[ak4 * 4 + 1][amA] = aPF0.y;
                S.u.l.As[ak4 * 4 + 2][amA] = aPF0.z;
                S.u.l.As[ak4 * 4 + 3][amA] = aPF0.w;
                S.u.l.As[ak4 * 4 + 0][64 + amA] = aPF1.x;
                S.u.l.As[ak4 * 4 + 1][64 + amA] = aPF1.y;
                S.u.l.As[ak4 * 4 + 2][64 + amA] = aPF1.z;
                S.u.l.As[ak4 * 4 + 3][64 + amA] = aPF1.w;
                *reinterpret_cast<float4*>(&S.u.l.Bs[bkB][bn4 * 4]) = bPF;
                __syncthreads();
                const int kn = k0 + 16;
                if (kn < 512) {
                    aPF0 = *reinterpret_cast<const float4*>(attn_new + (size_t)amA * 512 + kn + ak4 * 4);
                    aPF1 = *reinterpret_cast<const float4*>(attn_new + (size_t)(64 + amA) * 512 + kn + ak4 * 4);
                    bPF  = *reinterpret_cast<const float4*>(W_out + (size_t)(kn + bkB) * 32000 + n0 + bn4 * 4);
                }
                #pragma unroll
                for (int kk = 0; kk < 16; kk++) {
                    float af[8];
                    const float4 t0 = *reinterpret_cast<const float4*>(&S.u.l.As[kk][ty * 8]);
                    const float4 t1 = *reinterpret_cast<const float4*>(&S.u.l.As[kk][ty * 8 + 4]);
                    af[0] = t0.x; af[1] = t0.y; af[2] = t0.z; af[3] = t0.w;
                    af[4] = t1.x; af[5] = t1.y; af[6] = t1.z; af[7] = t1.w;
                    const float4 b4 = *reinterpret_cast<const float4*>(&S.u.l.Bs[kk][tx * 4]);
                    #pragma unroll
                    for (int i = 0; i < 8; i++) {
                        acc[i][0] += af[i] * b4.x; acc[i][1] += af[i] * b4.y;
                        acc[i][2] += af[i] * b4.z; acc[i][3] += af[i] * b4.w;
                    }
                }
                __syncthreads();
            }

            float bv[4];
            #pragma unroll
            for (int j = 0; j < 4; j++) bv[j] = b_out[n0 + tx * 4 + j];

            #pragma unroll
            for (int i = 0; i < 8; i++) {
                const int r = ty * 8 + i;
                float lv[4]; int lc[4];
                #pragma unroll
                for (int j = 0; j < 4; j++) { lv[j] = acc[i][j] + bv[j]; lc[j] = n0 + tx * 4 + j; }
                float rm = fmaxf(fmaxf(lv[0], lv[1]), fmaxf(lv[2], lv[3]));
                #pragma unroll
                for (int d = 1; d <= 8; d <<= 1) rm = fmaxf(rm, __shfl_xor(rm, d));
                float s4 = expf(lv[0] - rm) + expf(lv[1] - rm) + expf(lv[2] - rm) + expf(lv[3] - rm);
                #pragma unroll
                for (int d = 1; d <= 8; d <<= 1) s4 += __shfl_xor(s4, d);
                #pragma unroll
                for (int p = 0; p < 3; p++)
                    #pragma unroll
                    for (int q = 0; q < 3 - p; q++)
                        if (lv[q + 1] > lv[q]) {
                            const float tv = lv[q]; lv[q] = lv[q + 1]; lv[q + 1] = tv;
                            const int tc = lc[q]; lc[q] = lc[q + 1]; lc[q + 1] = tc;
                        }
                #pragma unroll
                for (int d = 1; d <= 8; d <<= 1) {
                    float rv[4]; int rc[4];
                    #pragma unroll
                    for (int j = 0; j < 4; j++) {
                        rv[j] = __shfl_xor(lv[j], d);
                        rc[j] = __shfl_xor(lc[j], d);
                    }
                    merge4_(lv, lc, rv, rc);
                }
                if (tx == 0) {
                    pmax[r * 512 + tile] = rm;
                    psum[r * 512 + tile] = s4;
                    #pragma unroll
                    for (int j = 0; j < 4; j++) {
                        pval[(r * 4 + j) * 512 + tile] = lv[j];
                        pcol[(r * 4 + j) * 512 + tile] = lc[j];
                    }
                }
            }
        }
        gsync_(bar, NB_DEC, gen, dead);

        // ---------------- phase 5: per-row merge of 500 tiles (128 blocks) --
        if (bid < 128) {
            const int r = bid;
            float m = -INFINITY, s = 0.f;
            float lv[4] = {-INFINITY, -INFINITY, -INFINITY, -INFINITY};
            int lc[4] = {0x7FFFFFFF, 0x7FFFFFFF, 0x7FFFFFFF, 0x7FFFFFFF};
            for (int tt = tid; tt < 500; tt += 256) {
                lse_combine_(m, s, pmax[r * 512 + tt], psum[r * 512 + tt]);
                float rv[4]; int rc[4];
                #pragma unroll
                for (int j = 0; j < 4; j++) {
                    rv[j] = pval[(r * 4 + j) * 512 + tt];
                    rc[j] = pcol[(r * 4 + j) * 512 + tt];
                }
                merge4_(lv, lc, rv, rc);
            }
            S.u.m.sm[tid] = m; S.u.m.ss[tid] = s;
            #pragma unroll
            for (int j = 0; j < 4; j++) { S.u.m.sv[tid][j] = lv[j]; S.u.m.sci[tid][j] = lc[j]; }
            __syncthreads();

            for (int st = 128; st >= 1; st >>= 1) {
                if (tid < st) {
                    lse_combine_(m, s, S.u.m.sm[tid + st], S.u.m.ss[tid + st]);
                    S.u.m.sm[tid] = m; S.u.m.ss[tid] = s;
                    float rv[4]; int rc[4];
                    #pragma unroll
                    for (int j = 0; j < 4; j++) {
                        rv[j] = S.u.m.sv[tid + st][j];
                        rc[j] = S.u.m.sci[tid + st][j];
                    }
                    merge4_(lv, lc, rv, rc);
                    #pragma unroll
                    for (int j = 0; j < 4; j++) { S.u.m.sv[tid][j] = lv[j]; S.u.m.sci[tid][j] = lc[j]; }
                }
                __syncthreads();
            }
            if (tid == 0) {
                rowlse_g[r] = m + logf(s);
                #pragma unroll
                for (int j = 0; j < 4; j++) { rowv_g[r * 4 + j] = lv[j]; rowc_g[r * 4 + j] = lc[j]; }
            }
        }
        gsync_(bar, NB_DEC, gen, dead);

        // ---------------- phase 6: beam select + state gather (32 blocks) ---
        if (bid < 32) {
            const int b = bid;
            if (tid == 0) {
                float oldcum[4]; int oldfin[4];
                for (int k = 0; k < 4; k++) {
                    oldcum[k] = cum[b * 4 + k];
                    oldfin[k] = fin[b * 4 + k];
                }
                float cv[16]; int ci[16];
                const int fillv[3] = {0, 1, 3};
                for (int k = 0; k < 4; k++) {
                    if (oldfin[k]) {
                        cv[k * 4 + 0] = oldcum[k];
                        ci[k * 4 + 0] = k * 32000 + EOS_ID;
                        for (int j = 1; j < 4; j++) {
                            cv[k * 4 + j] = oldcum[k] + NEGV;
                            ci[k * 4 + j] = k * 32000 + fillv[j - 1];
                        }
                    } else {
                        const float lse = rowlse_g[b * 4 + k];
                        for (int j = 0; j < 4; j++) {
                            cv[k * 4 + j] = oldcum[k] + (rowv_g[(b * 4 + k) * 4 + j] - lse);
                            ci[k * 4 + j] = k * 32000 + rowc_g[(b * 4 + k) * 4 + j];
                        }
                    }
                }
                for (int rr = 0; rr < 4; rr++) {
                    float bvv = -INFINITY; int bix = 0x7FFFFFFF, bp_ = -1;
                    for (int q = 0; q < 16; q++) {
                        if (cv[q] > bvv || (cv[q] == bvv && ci[q] < bix)) {
                            bvv = cv[q]; bix = ci[q]; bp_ = q;
                        }
                    }
                    cv[bp_] = -INFINITY; ci[bp_] = 0x7FFFFFFF;
                    const int k = (bix / 32000) & 3;      // safety clamp
                    const int v = bix - (bix / 32000) * 32000;
                    S.par[rr] = k;
                    parents[step * 128 + b * 4 + rr] = k;
                    toks[step * 128 + b * 4 + rr] = v;
                    cum[b * 4 + rr] = bvv;
                    tok[b * 4 + rr] = v;
                    fin[b * 4 + rr] = (oldfin[k] || v == EOS_ID) ? 1 : 0;
                }
            }
            __syncthreads();
            for (int idx = tid; idx < 4 * 512; idx += 256) {
                const int j = idx >> 9, col = idx & 511;
                const int sr = b * 4 + S.par[j], dr = b * 4 + j;
                h_buf[(size_t)dr * 512 + col] = Acat[(size_t)sr * 1024 + col];
                c_buf[(size_t)dr * 512 + col] = c_new[(size_t)sr * 512 + col];
                attn_buf[(size_t)dr * 512 + col] = attn_new[(size_t)sr * 512 + col];
            }
        }
        gsync_(bar, NB_DEC, gen, dead);
    }
}

// ---------------------------------------------------------------------------
__global__ void __launch_bounds__(128) backtrack_k(
    const int* __restrict__ parents, const int* __restrict__ toks,
    int* __restrict__ out)
{
    const int tid = threadIdx.x;
    const int b = tid >> 2, kc = tid & 3;
    int ptr = kc;
    for (int t = 47; t >= 0; --t) {
        out[b * 192 + t * 4 + kc] = toks[t * 128 + b * 4 + ptr];
        ptr = parents[t * 128 + b * 4 + ptr] & 3;   // safety clamp
    }
}

// ---------------------------------------------------------------------------
extern "C" void kernel_launch(void* const* d_in, const int* in_sizes, int n_in,
                              void* d_out, int out_size, void* d_ws, size_t ws_size,
                              hipStream_t stream)
{
    (void)in_sizes; (void)n_in; (void)out_size; (void)ws_size;
    const int* enc_in = (const int*)d_in[0];
    const float* enc_emb = (const float*)d_in[2];
    const float* dec_emb = (const float*)d_in[3];
    const float* W_enc = (const float*)d_in[4];
    const float* U_enc = (const float*)d_in[5];
    const float* b_enc = (const float*)d_in[6];
    const float* W_dec = (const float*)d_in[7];
    const float* U_dec = (const float*)d_in[8];
    const float* b_dec = (const float*)d_in[9];
    const float* W_mem = (const float*)d_in[10];
    const float* W_attn = (const float*)d_in[11];
    const float* W_out = (const float*)d_in[12];
    const float* b_out = (const float*)d_in[13];
    int* out = (int*)d_out;

    char* ws = (char*)d_ws;
    size_t off = 0;
    auto alloc = [&](size_t bytes) -> char* {
        char* p = ws + off;
        off = (off + bytes + 255) & ~(size_t)255;
        return p;
    };
    float* Xz       = (float*)alloc(128ull * 32 * 2048 * 4);
    float* enc_out  = (float*)alloc(32ull * 128 * 512 * 4);
    float* keysT    = (float*)alloc(32ull * 512 * 128 * 4);
    float* Bp       = (float*)alloc(1536ull * 2048 * 4);
    float* bp       = (float*)alloc(2048 * 4);
    float* enc_c    = (float*)alloc(32ull * 512 * 4);
    float* hzero    = (float*)alloc(512 * 4);
    float* h_buf    = (float*)alloc(128ull * 512 * 4);
    float* c_buf    = (float*)alloc(128ull * 512 * 4);
    float* attn_buf = (float*)alloc(128ull * 512 * 4);
    float* c_new    = (float*)alloc(128ull * 512 * 4);
    float* Acat     = (float*)alloc(128ull * 1024 * 4);
    float* attn_new = (float*)alloc(128ull * 512 * 4);
    float* pmax     = (float*)alloc(128ull * 512 * 4);
    float* psum     = (float*)alloc(128ull * 512 * 4);
    float* pval     = (float*)alloc(512ull * 512 * 4);
    int*   pcol     = (int*)alloc(512ull * 512 * 4);
    float* cum      = (float*)alloc(128 * 4);
    int* fin        = (int*)alloc(128 * 4);
    int* tok        = (int*)alloc(128 * 4);
    int* parents    = (int*)alloc(48 * 128 * 4);
    int* toks       = (int*)alloc(48 * 128 * 4);
    float* rowlse_g = (float*)alloc(128 * 4);
    float* rowv_g   = (float*)alloc(512 * 4);
    int*   rowc_g   = (int*)alloc(512 * 4);
    int*   barA     = (int*)alloc(256);
    int*   barB     = (int*)alloc(256);

    pack_dec_k<<<(1536 * 2048) / 256, 256, 0, stream>>>(W_dec, U_dec, b_dec, Bp, bp,
                                                        enc_c, hzero, barA, barB);

    gemm_k<64, 64, 16, 2, 0><<<dim3(32, 64), 256, 0, stream>>>(
        enc_emb, W_enc, b_enc, Xz, 4096, 2048, 512, enc_in);

    enc_persist_k<<<128, 256, 0, stream>>>(Xz, hzero, U_enc, enc_c, enc_out, barA);

    gemm_k<64, 64, 16, 0, 1><<<dim3(8, 64), 256, 0, stream>>>(
        enc_out, W_mem, nullptr, keysT, 4096, 512, 512, nullptr);

    init_dec_k<<<256, 256, 0, stream>>>(enc_out, enc_c, h_buf, c_buf, attn_buf,
                                        cum, fin, tok);

    dec_persist_k<<<NB_DEC, 256, 0, stream>>>(
        dec_emb, Bp, bp, tok, attn_buf, h_buf, c_buf, c_new, Acat, keysT,
        enc_out, W_attn, attn_new, W_out, b_out, pmax, psum, pval, pcol,
        cum, fin, parents, toks, rowlse_g, rowv_g, rowc_g, barB);

    backtrack_k<<<1, 128, 0, stream>>>(parents, toks, out);
}

// Round 4
// 11492.297 us; speedup vs baseline: 2.3020x; 2.3020x over previous
//
#include <hip/hip_runtime.h>
#include <math.h>

#define EOS_ID 2
#define START_ID 1
#define NEGV (-1e9f)

__device__ __forceinline__ float sigmoidf_(float x) { return 1.f / (1.f + expf(-x)); }

// merge two desc-sorted (val, col) top-4 lists; tie: lower col wins. Result into l*.
__device__ __forceinline__ void merge4_(float lv[4], int lc[4],
                                        const float rv[4], const int rc[4]) {
    float ov[4]; int oc[4];
    int ai = 0, bi = 0;
    #pragma unroll
    for (int o = 0; o < 4; o++) {
        const float avv = (ai == 0) ? lv[0] : (ai == 1) ? lv[1] : (ai == 2) ? lv[2] : lv[3];
        const int   acc = (ai == 0) ? lc[0] : (ai == 1) ? lc[1] : (ai == 2) ? lc[2] : lc[3];
        const float bvv = (bi == 0) ? rv[0] : (bi == 1) ? rv[1] : (bi == 2) ? rv[2] : rv[3];
        const int   bcc = (bi == 0) ? rc[0] : (bi == 1) ? rc[1] : (bi == 2) ? rc[2] : rc[3];
        const bool ta = (avv > bvv) || (avv == bvv && acc < bcc);
        ov[o] = ta ? avv : bvv;
        oc[o] = ta ? acc : bcc;
        if (ta) ai++; else bi++;
    }
    #pragma unroll
    for (int o = 0; o < 4; o++) { lv[o] = ov[o]; lc[o] = oc[o]; }
}

__device__ __forceinline__ void lse_combine_(float& m, float& s, float m2, float s2) {
    const float M = fmaxf(m, m2);
    s = s * expf(m - M) + s2 * expf(m2 - M);
    m = M;
}

// ---------------------------------------------------------------------------
// Generic fp32 GEMM (reg-staged prefetch). Used for Xz (AMODE 2) and keysT
// (TRANS 1) only — both wide one-shot launches.
// ---------------------------------------------------------------------------
template<int BM, int BN, int BK, int AMODE, int TRANS>
__global__ void __launch_bounds__(256) gemm_k(
    const float* __restrict__ A, const float* __restrict__ B,
    const float* __restrict__ bias, float* __restrict__ C,
    int M, int N, int K, const int* __restrict__ tokp)
{
    static_assert(BN == 64, "");
    constexpr int TM = BM / 16, TN = BN / 16;
    __shared__ __align__(16) float As[BK][BM];
    __shared__ __align__(16) float Bs[BK][BN];
    const int tid = threadIdx.x;
    const int n0 = blockIdx.x * BN, m0 = blockIdx.y * BM;
    const int tx = tid & 15, ty = tid >> 4;
    (void)M;

    float acc[TM][TN];
    #pragma unroll
    for (int i = 0; i < TM; i++)
        #pragma unroll
        for (int j = 0; j < TN; j++) acc[i][j] = 0.f;

    constexpr int A4 = BM * BK / 4;
    const bool aP = (A4 >= 256) || (tid < A4);
    const int am = tid / (BK / 4), ak4 = tid % (BK / 4);
    const int bk = tid >> 4, bn4 = tid & 15;

    const float* aRow = nullptr;
    if (aP) {
        if (AMODE == 0) {
            aRow = A + (size_t)(m0 + am) * K;
        } else {  // AMODE 2: gather embedding row once
            const int r = m0 + am;
            const int s = r >> 5, bidx = r & 31;
            aRow = A + (size_t)tokp[bidx * 128 + s] * 512;
        }
    }

    float4 aPF{}, bPF;
    if (aP) aPF = *reinterpret_cast<const float4*>(aRow + ak4 * 4);
    bPF = *reinterpret_cast<const float4*>(B + (size_t)bk * N + n0 + bn4 * 4);

    for (int k0 = 0; k0 < K; k0 += BK) {
        if (aP) {
            As[ak4 * 4 + 0][am] = aPF.x;
            As[ak4 * 4 + 1][am] = aPF.y;
            As[ak4 * 4 + 2][am] = aPF.z;
            As[ak4 * 4 + 3][am] = aPF.w;
        }
        *reinterpret_cast<float4*>(&Bs[bk][bn4 * 4]) = bPF;
        __syncthreads();
        const int kn = k0 + BK;
        if (kn < K) {
            if (aP) aPF = *reinterpret_cast<const float4*>(aRow + kn + ak4 * 4);
            bPF = *reinterpret_cast<const float4*>(B + (size_t)(kn + bk) * N + n0 + bn4 * 4);
        }
        #pragma unroll
        for (int kk = 0; kk < BK; kk++) {
            float af[TM], bf[TN];
            if constexpr (TM == 4) {
                const float4 t4 = *reinterpret_cast<const float4*>(&As[kk][ty * TM]);
                af[0] = t4.x; af[1] = t4.y; af[2] = t4.z; af[3] = t4.w;
            } else if constexpr (TM == 2) {
                const float2 t2 = *reinterpret_cast<const float2*>(&As[kk][ty * TM]);
                af[0] = t2.x; af[1] = t2.y;
            } else {
                af[0] = As[kk][ty];
            }
            const float4 b4 = *reinterpret_cast<const float4*>(&Bs[kk][tx * TN]);
            bf[0] = b4.x; bf[1] = b4.y; bf[2] = b4.z; bf[3] = b4.w;
            #pragma unroll
            for (int i = 0; i < TM; i++)
                #pragma unroll
                for (int j = 0; j < TN; j++) acc[i][j] += af[i] * bf[j];
        }
        __syncthreads();
    }

    if constexpr (TRANS) {
        #pragma unroll
        for (int i = 0; i < TM; i++) {
            const int r = m0 + ty * TM + i;
            const int b = r >> 7, s = r & 127;
            #pragma unroll
            for (int j = 0; j < TN; j++)
                C[((size_t)b * 512 + (n0 + tx * TN + j)) * 128 + s] = acc[i][j];
        }
    } else {
        float bv[TN];
        #pragma unroll
        for (int j = 0; j < TN; j++) bv[j] = bias ? bias[n0 + tx * TN + j] : 0.f;
        #pragma unroll
        for (int i = 0; i < TM; i++) {
            float4 o;
            o.x = acc[i][0] + bv[0]; o.y = acc[i][1] + bv[1];
            o.z = acc[i][2] + bv[2]; o.w = acc[i][3] + bv[3];
            *reinterpret_cast<float4*>(C + (size_t)(m0 + ty * TM + i) * N + n0 + tx * TN) = o;
        }
    }
}

// ---------------------------------------------------------------------------
// One-time pack + zero-init of enc_c/hzero.
// ---------------------------------------------------------------------------
__global__ void __launch_bounds__(256) pack_dec_k(
    const float* __restrict__ W_dec, const float* __restrict__ U_dec,
    const float* __restrict__ b_dec, float* __restrict__ Bp, float* __restrict__ bp,
    float* __restrict__ enc_c, float* __restrict__ hzero)
{
    const int idx = blockIdx.x * 256 + threadIdx.x;
    if (idx < 1536 * 2048) {
        const int k = idx >> 11, cp = idx & 2047;
        const int j = cp >> 2, g = cp & 3;
        const int sc = g * 512 + j;
        Bp[idx] = (k < 1024) ? W_dec[(size_t)k * 2048 + sc]
                             : U_dec[(size_t)(k - 1024) * 2048 + sc];
        if (idx < 2048) bp[idx] = b_dec[sc];
    }
    if (idx < 32 * 512) enc_c[idx] = 0.f;
    if (idx < 512) hzero[idx] = 0.f;
}

// ---------------------------------------------------------------------------
// Encoder LSTM step (round-1-verified). Grid (16 jtiles, 16 bgroups), block 256.
// ---------------------------------------------------------------------------
__global__ void __launch_bounds__(256) enc_step_k(
    const float* __restrict__ Xz_t, const float* __restrict__ hprev, long hstride,
    const float* __restrict__ U, float* __restrict__ c, float* __restrict__ hout)
{
    __shared__ __align__(16) float hs[512][2];
    __shared__ __align__(16) float zp[8][2][128];
    __shared__ float zfin[2][32][4];
    const int tid = threadIdx.x;
    const int jt = blockIdx.x;          // 0..15, 32 j-values each
    const int b0 = blockIdx.y * 2;

    {
        const int bb = tid >> 7, k4 = tid & 127;
        const float4 hv = *reinterpret_cast<const float4*>(
            hprev + (size_t)(b0 + bb) * hstride + k4 * 4);
        hs[k4 * 4 + 0][bb] = hv.x; hs[k4 * 4 + 1][bb] = hv.y;
        hs[k4 * 4 + 2][bb] = hv.z; hs[k4 * 4 + 3][bb] = hv.w;
    }
    __syncthreads();

    {
        const int kp = tid >> 5, cq = tid & 31;
        const int g = cq >> 3, j4 = (cq & 7) * 4;
        const int col = g * 512 + jt * 32 + j4;
        const int kbase = kp * 64;
        float4 A0 = {0.f, 0.f, 0.f, 0.f}, A1 = {0.f, 0.f, 0.f, 0.f};
        #pragma unroll 8
        for (int k = 0; k < 64; k++) {
            const float4 u4 = *reinterpret_cast<const float4*>(
                U + (size_t)(kbase + k) * 2048 + col);
            const float2 h2 = *reinterpret_cast<const float2*>(&hs[kbase + k][0]);
            A0.x += h2.x * u4.x; A0.y += h2.x * u4.y;
            A0.z += h2.x * u4.z; A0.w += h2.x * u4.w;
            A1.x += h2.y * u4.x; A1.y += h2.y * u4.y;
            A1.z += h2.y * u4.z; A1.w += h2.y * u4.w;
        }
        *reinterpret_cast<float4*>(&zp[kp][0][g * 32 + j4]) = A0;
        *reinterpret_cast<float4*>(&zp[kp][1][g * 32 + j4]) = A1;
    }
    __syncthreads();

    {
        const int bb = tid >> 7, rem = tid & 127;
        const int jj = rem >> 2, gg2 = rem & 3;
        float s = 0.f;
        #pragma unroll
        for (int p = 0; p < 8; p++) s += zp[p][bb][gg2 * 32 + jj];
        s += Xz_t[(size_t)(b0 + bb) * 2048 + gg2 * 512 + jt * 32 + jj];
        zfin[bb][jj][gg2] = s;
    }
    __syncthreads();

    if (tid < 64) {
        const int bb = tid >> 5, jj = tid & 31;
        const int b = b0 + bb;
        const float iv = sigmoidf_(zfin[bb][jj][0]);
        const float fv = sigmoidf_(zfin[bb][jj][1]);
        const float gv = tanhf(zfin[bb][jj][2]);
        const float ov = sigmoidf_(zfin[bb][jj][3]);
        const int jglob = jt * 32 + jj;
        const size_t ci = (size_t)b * 512 + jglob;
        const float cv = fv * c[ci] + iv * gv;
        c[ci] = cv;
        hout[(size_t)b * 128 * 512 + jglob] = ov * tanhf(cv);
    }
}

// ---------------------------------------------------------------------------
// Decoder init: populate "prev" buffers for step 0 + identity parents.
// ---------------------------------------------------------------------------
__global__ void __launch_bounds__(256) init_dec_k(
    const float* __restrict__ enc_out, const float* __restrict__ enc_c,
    float* __restrict__ ho_p, float* __restrict__ c_p, float* __restrict__ at_p,
    float* __restrict__ cum, int* __restrict__ fin, int* __restrict__ tok,
    int* __restrict__ parc)
{
    const int idx = blockIdx.x * 256 + threadIdx.x;
    const int r = idx >> 9, jcol = idx & 511;
    const int b = r >> 2, kbeam = r & 3;
    ho_p[idx] = enc_out[((size_t)b * 128 + 127) * 512 + jcol];
    c_p[idx] = enc_c[(size_t)b * 512 + jcol];
    at_p[idx] = 0.f;
    if (jcol == 0) {
        cum[r] = (kbeam == 0) ? 0.f : NEGV;
        fin[r] = 0;
        tok[r] = START_ID;
        parc[r] = kbeam;     // identity parent for step 0
    }
}

// ---------------------------------------------------------------------------
// z GEMM with concat-gather A (parent-indirected state) and fused LSTM gate
// epilogue (packed B), reg-staged prefetch. BM=16, BN=64, BK=16. Grid (32,8).
// A = [emb(tok[r]) | at_p[par[r]] | ho_p[par[r]]], K=1536. c from c_p[par[r]].
// ---------------------------------------------------------------------------
__global__ void __launch_bounds__(256) zgemm_gates_k(
    const float* __restrict__ dec_emb, const float* __restrict__ Bp,
    const float* __restrict__ bp, const int* __restrict__ tok,
    const int* __restrict__ parc,
    const float* __restrict__ at_p, const float* __restrict__ ho_p,
    const float* __restrict__ c_p, float* __restrict__ c_c,
    float* __restrict__ ho_c)
{
    constexpr int BK = 16;
    __shared__ __align__(16) float As[BK][16];
    __shared__ __align__(16) float Bs[BK][64];
    const int tid = threadIdx.x;
    const int n0 = blockIdx.x * 64, m0 = blockIdx.y * 16;
    const int tx = tid & 15, ty = tid >> 4;

    float acc[4] = {0.f, 0.f, 0.f, 0.f};

    const bool aP = tid < 64;
    const int am = tid >> 2, ak4 = tid & 3;
    const int r = m0 + am;
    const int bk = tid >> 4, bn4 = tid & 15;
    const float* embRow = nullptr;
    int sr = 0;
    if (aP) {
        embRow = dec_emb + (size_t)tok[r] * 512;
        sr = (r & ~3) | parc[r];
    }

    auto loadA = [&](int k0) -> float4 {
        const int kg = k0 + ak4 * 4;
        if (kg < 512)
            return *reinterpret_cast<const float4*>(embRow + kg);
        if (kg < 1024)
            return *reinterpret_cast<const float4*>(at_p + (size_t)sr * 512 + (kg - 512));
        return *reinterpret_cast<const float4*>(ho_p + (size_t)sr * 512 + (kg - 1024));
    };

    float4 aPF{}, bPF;
    if (aP) aPF = loadA(0);
    bPF = *reinterpret_cast<const float4*>(Bp + (size_t)bk * 2048 + n0 + bn4 * 4);

    for (int k0 = 0; k0 < 1536; k0 += BK) {
        if (aP) {
            As[ak4 * 4 + 0][am] = aPF.x;
            As[ak4 * 4 + 1][am] = aPF.y;
            As[ak4 * 4 + 2][am] = aPF.z;
            As[ak4 * 4 + 3][am] = aPF.w;
        }
        *reinterpret_cast<float4*>(&Bs[bk][bn4 * 4]) = bPF;
        __syncthreads();
        const int kn = k0 + BK;
        if (kn < 1536) {
            if (aP) aPF = loadA(kn);
            bPF = *reinterpret_cast<const float4*>(Bp + (size_t)(kn + bk) * 2048 + n0 + bn4 * 4);
        }
        #pragma unroll
        for (int kk = 0; kk < BK; kk++) {
            const float a = As[kk][ty];
            const float4 b4 = *reinterpret_cast<const float4*>(&Bs[kk][tx * 4]);
            acc[0] += a * b4.x; acc[1] += a * b4.y;
            acc[2] += a * b4.z; acc[3] += a * b4.w;
        }
        __syncthreads();
    }

    const int rr = m0 + ty;
    const int sre = (rr & ~3) | parc[rr];
    const int j = (n0 >> 2) + tx;
    const float iv = sigmoidf_(acc[0] + bp[n0 + tx * 4 + 0]);
    const float fv = sigmoidf_(acc[1] + bp[n0 + tx * 4 + 1]);
    const float gv = tanhf   (acc[2] + bp[n0 + tx * 4 + 2]);
    const float ov = sigmoidf_(acc[3] + bp[n0 + tx * 4 + 3]);
    const float cv = fv * c_p[(size_t)sre * 512 + j] + iv * gv;
    c_c[(size_t)rr * 512 + j] = cv;
    ho_c[(size_t)rr * 512 + j] = ov * tanhf(cv);
}

// ---------------------------------------------------------------------------
// Fused attention + attention-layer GEMM. Grid 128 (one row), block 256.
// ctx never leaves LDS; projection loop k ascending == bitwise-identical to
// the former separate gemm_k<16,64,16> (same per-column fp add order).
// ---------------------------------------------------------------------------
__global__ void __launch_bounds__(256) attn_fused_k(
    const float* __restrict__ ho_c, const float* __restrict__ keysT,
    const float* __restrict__ enc_out, const float* __restrict__ W_attn,
    float* __restrict__ at_c)
{
    __shared__ __align__(16) float q[1024];       // [cell(512) | ctx(512)]
    __shared__ float scp[2][128];
    __shared__ float sc[128];
    __shared__ float red[128];
    const int r = blockIdx.x;
    const int b = r >> 2;
    const int tid = threadIdx.x;

    if (tid < 128)
        reinterpret_cast<float4*>(q)[tid] =
            reinterpret_cast<const float4*>(ho_c + (size_t)r * 512)[tid];
    __syncthreads();

    {
        const int half = tid >> 7, s = tid & 127;
        const float* kp = keysT + ((size_t)b * 512 + half * 256) * 128 + s;
        float acc = 0.f;
        #pragma unroll 8
        for (int kk = 0; kk < 256; kk++) acc += q[half * 256 + kk] * kp[(size_t)kk * 128];
        scp[half][s] = acc;
    }
    __syncthreads();
    if (tid < 128) sc[tid] = scp[0][tid] + scp[1][tid];
    __syncthreads();
    if (tid < 64) red[tid] = fmaxf(sc[tid], sc[tid + 64]);
    __syncthreads();
    for (int st = 32; st >= 1; st >>= 1) {
        if (tid < st) red[tid] = fmaxf(red[tid], red[tid + st]);
        __syncthreads();
    }
    const float m = red[0];
    __syncthreads();
    if (tid < 128) sc[tid] = expf(sc[tid] - m);
    __syncthreads();
    if (tid < 64) red[tid] = sc[tid] + sc[tid + 64];
    __syncthreads();
    for (int st = 32; st >= 1; st >>= 1) {
        if (tid < st) red[tid] += red[tid + st];
        __syncthreads();
    }
    const float S = red[0];
    __syncthreads();
    if (tid < 128) sc[tid] = sc[tid] / S;
    __syncthreads();

    {
        float a0 = 0.f, a1 = 0.f;
        for (int s = 0; s < 128; s++) {
            const float w = sc[s];
            const float* vr = enc_out + ((size_t)b * 128 + s) * 512;
            a0 += w * vr[tid];
            a1 += w * vr[tid + 256];
        }
        q[512 + tid] = a0;
        q[512 + 256 + tid] = a1;
    }
    __syncthreads();

    // projection: at_c[r][n] = sum_k q[k] * W_attn[k][n]; thread -> cols 2t,2t+1
    {
        const int n = tid * 2;
        float acc0 = 0.f, acc1 = 0.f;
        const float* wp = W_attn + n;
        #pragma unroll 8
        for (int k = 0; k < 1024; k++) {
            const float2 w2 = *reinterpret_cast<const float2*>(wp + (size_t)k * 512);
            const float a = q[k];
            acc0 += a * w2.x;
            acc1 += a * w2.y;
        }
        float2 o; o.x = acc0; o.y = acc1;
        *reinterpret_cast<float2*>(at_c + (size_t)r * 512 + n) = o;
    }
}

// ---------------------------------------------------------------------------
// Logits GEMM (BM=128 x BN=64, K=512) with reg-staged prefetch pipeline and
// fused per-row-per-tile partials: rowmax, sumexp(rel max), top-4
// (val desc, col asc). Logits never hit memory. Grid 500 (1D).
// ---------------------------------------------------------------------------
__global__ void __launch_bounds__(256) logits_top_k(
    const float* __restrict__ A, const float* __restrict__ B,
    const float* __restrict__ bias, float* __restrict__ pmax,
    float* __restrict__ psum, float* __restrict__ pval, int* __restrict__ pcol)
{
    constexpr int BK = 16;
    __shared__ __align__(16) float As[BK][128];
    __shared__ __align__(16) float Bs[BK][64];
    const int tid = threadIdx.x;
    const int n0 = blockIdx.x * 64;
    const int t = blockIdx.x;
    const int tx = tid & 15, ty = tid >> 4;

    float acc[8][4];
    #pragma unroll
    for (int i = 0; i < 8; i++)
        #pragma unroll
        for (int j = 0; j < 4; j++) acc[i][j] = 0.f;

    const int amA = tid >> 2, ak4 = tid & 3;
    const int bkB = tid >> 4, bn4 = tid & 15;

    float4 aPF0 = *reinterpret_cast<const float4*>(A + (size_t)amA * 512 + ak4 * 4);
    float4 aPF1 = *reinterpret_cast<const float4*>(A + (size_t)(64 + amA) * 512 + ak4 * 4);
    float4 bPF  = *reinterpret_cast<const float4*>(B + (size_t)bkB * 32000 + n0 + bn4 * 4);

    for (int k0 = 0; k0 < 512; k0 += BK) {
        As[ak4 * 4 + 0][amA] = aPF0.x;
        As[ak4 * 4 + 1][amA] = aPF0.y;
        As[ak4 * 4 + 2][amA] = aPF0.z;
        As[ak4 * 4 + 3][amA] = aPF0.w;
        As[ak4 * 4 + 0][64 + amA] = aPF1.x;
        As[ak4 * 4 + 1][64 + amA] = aPF1.y;
        As[ak4 * 4 + 2][64 + amA] = aPF1.z;
        As[ak4 * 4 + 3][64 + amA] = aPF1.w;
        *reinterpret_cast<float4*>(&Bs[bkB][bn4 * 4]) = bPF;
        __syncthreads();
        const int kn = k0 + BK;
        if (kn < 512) {
            aPF0 = *reinterpret_cast<const float4*>(A + (size_t)amA * 512 + kn + ak4 * 4);
            aPF1 = *reinterpret_cast<const float4*>(A + (size_t)(64 + amA) * 512 + kn + ak4 * 4);
            bPF  = *reinterpret_cast<const float4*>(B + (size_t)(kn + bkB) * 32000 + n0 + bn4 * 4);
        }
        #pragma unroll
        for (int kk = 0; kk < BK; kk++) {
            float af[8];
            const float4 t0 = *reinterpret_cast<const float4*>(&As[kk][ty * 8]);
            const float4 t1 = *reinterpret_cast<const float4*>(&As[kk][ty * 8 + 4]);
            af[0] = t0.x; af[1] = t0.y; af[2] = t0.z; af[3] = t0.w;
            af[4] = t1.x; af[5] = t1.y; af[6] = t1.z; af[7] = t1.w;
            const float4 b4 = *reinterpret_cast<const float4*>(&Bs[kk][tx * 4]);
            #pragma unroll
            for (int i = 0; i < 8; i++) {
                acc[i][0] += af[i] * b4.x; acc[i][1] += af[i] * b4.y;
                acc[i][2] += af[i] * b4.z; acc[i][3] += af[i] * b4.w;
            }
        }
        __syncthreads();
    }

    float bv[4];
    #pragma unroll
    for (int j = 0; j < 4; j++) bv[j] = bias[n0 + tx * 4 + j];

    #pragma unroll
    for (int i = 0; i < 8; i++) {
        const int r = ty * 8 + i;
        float lv[4]; int lc[4];
        #pragma unroll
        for (int j = 0; j < 4; j++) { lv[j] = acc[i][j] + bv[j]; lc[j] = n0 + tx * 4 + j; }
        float rm = fmaxf(fmaxf(lv[0], lv[1]), fmaxf(lv[2], lv[3]));
        #pragma unroll
        for (int d = 1; d <= 8; d <<= 1) rm = fmaxf(rm, __shfl_xor(rm, d));
        float s4 = expf(lv[0] - rm) + expf(lv[1] - rm) + expf(lv[2] - rm) + expf(lv[3] - rm);
        #pragma unroll
        for (int d = 1; d <= 8; d <<= 1) s4 += __shfl_xor(s4, d);
        #pragma unroll
        for (int p = 0; p < 3; p++)
            #pragma unroll
            for (int q = 0; q < 3 - p; q++)
                if (lv[q + 1] > lv[q]) {
                    const float tv = lv[q]; lv[q] = lv[q + 1]; lv[q + 1] = tv;
                    const int tc = lc[q]; lc[q] = lc[q + 1]; lc[q + 1] = tc;
                }
        #pragma unroll
        for (int d = 1; d <= 8; d <<= 1) {
            float rv[4]; int rc[4];
            #pragma unroll
            for (int j = 0; j < 4; j++) {
                rv[j] = __shfl_xor(lv[j], d);
                rc[j] = __shfl_xor(lc[j], d);
            }
            merge4_(lv, lc, rv, rc);
        }
        if (tx == 0) {
            pmax[r * 512 + t] = rm;
            psum[r * 512 + t] = s4;
            #pragma unroll
            for (int j = 0; j < 4; j++) {
                pval[(r * 4 + j) * 512 + t] = lv[j];
                pcol[(r * 4 + j) * 512 + t] = lc[j];
            }
        }
    }
}

// ---------------------------------------------------------------------------
// Per-batch: merge 500 tile-partials for the 4 beam rows (lockstep, 4x256
// threads), then beam top-4 with exact jax tie-break. NO state gather —
// writes parent indices (parc) consumed by next step's zgemm indirection.
// Grid 32, block 1024.
// ---------------------------------------------------------------------------
__global__ void __launch_bounds__(1024) merge_update_k(
    const float* __restrict__ pmax, const float* __restrict__ psum,
    const float* __restrict__ pval, const int* __restrict__ pcol,
    float* __restrict__ cum, int* __restrict__ fin, int* __restrict__ tok,
    int* __restrict__ parc,
    int* __restrict__ parents_t, int* __restrict__ toks_t)
{
    const int b = blockIdx.x;
    const int tid = threadIdx.x;
    const int rloc = tid >> 8, lt = tid & 255;
    const int r = b * 4 + rloc;

    __shared__ float sm[4][256], ss[4][256];
    __shared__ float sv[4][256][4];
    __shared__ int   sc4[4][256][4];
    __shared__ float rowlse[4], rowv[4][4];
    __shared__ int   rowc[4][4];
    __shared__ float oldcum[4];
    __shared__ int   oldfin[4];

    if (tid < 4) {
        oldcum[tid] = cum[b * 4 + tid];
        oldfin[tid] = fin[b * 4 + tid];
    }

    float m = -INFINITY, s = 0.f;
    float lv[4] = {-INFINITY, -INFINITY, -INFINITY, -INFINITY};
    int lc[4] = {0x7FFFFFFF, 0x7FFFFFFF, 0x7FFFFFFF, 0x7FFFFFFF};
    for (int t = lt; t < 500; t += 256) {
        lse_combine_(m, s, pmax[r * 512 + t], psum[r * 512 + t]);
        float rv[4]; int rc[4];
        #pragma unroll
        for (int j = 0; j < 4; j++) {
            rv[j] = pval[(r * 4 + j) * 512 + t];
            rc[j] = pcol[(r * 4 + j) * 512 + t];
        }
        merge4_(lv, lc, rv, rc);
    }
    sm[rloc][lt] = m; ss[rloc][lt] = s;
    #pragma unroll
    for (int j = 0; j < 4; j++) { sv[rloc][lt][j] = lv[j]; sc4[rloc][lt][j] = lc[j]; }
    __syncthreads();

    for (int st = 128; st >= 1; st >>= 1) {
        if (lt < st) {
            float m2 = sm[rloc][lt + st], s2 = ss[rloc][lt + st];
            lse_combine_(m, s, m2, s2);
            sm[rloc][lt] = m; ss[rloc][lt] = s;
            float rv[4]; int rc[4];
            #pragma unroll
            for (int j = 0; j < 4; j++) {
                rv[j] = sv[rloc][lt + st][j];
                rc[j] = sc4[rloc][lt + st][j];
            }
            merge4_(lv, lc, rv, rc);
            #pragma unroll
            for (int j = 0; j < 4; j++) { sv[rloc][lt][j] = lv[j]; sc4[rloc][lt][j] = lc[j]; }
        }
        __syncthreads();
    }
    if (lt == 0) {
        rowlse[rloc] = m + logf(s);
        #pragma unroll
        for (int j = 0; j < 4; j++) { rowv[rloc][j] = lv[j]; rowc[rloc][j] = lc[j]; }
    }
    __syncthreads();

    if (tid == 0) {
        float cv[16]; int ci[16];
        const int fillv[3] = {0, 1, 3};
        for (int k = 0; k < 4; k++) {
            if (oldfin[k]) {
                cv[k * 4 + 0] = oldcum[k];
                ci[k * 4 + 0] = k * 32000 + EOS_ID;
                for (int j = 1; j < 4; j++) {
                    cv[k * 4 + j] = oldcum[k] + NEGV;
                    ci[k * 4 + j] = k * 32000 + fillv[j - 1];
                }
            } else {
                const float lse = rowlse[k];
                for (int j = 0; j < 4; j++) {
                    cv[k * 4 + j] = oldcum[k] + (rowv[k][j] - lse);
                    ci[k * 4 + j] = k * 32000 + rowc[k][j];
                }
            }
        }
        for (int rr = 0; rr < 4; rr++) {
            float bvv = -INFINITY; int bix = 0x7FFFFFFF, bp_ = -1;
            for (int q = 0; q < 16; q++) {
                if (cv[q] > bvv || (cv[q] == bvv && ci[q] < bix)) {
                    bvv = cv[q]; bix = ci[q]; bp_ = q;
                }
            }
            cv[bp_] = -INFINITY; ci[bp_] = 0x7FFFFFFF;
            const int k = bix / 32000, v = bix - k * 32000;
            parc[b * 4 + rr] = k;
            parents_t[b * 4 + rr] = k;
            toks_t[b * 4 + rr] = v;
            cum[b * 4 + rr] = bvv;
            tok[b * 4 + rr] = v;
            fin[b * 4 + rr] = (oldfin[k] || v == EOS_ID) ? 1 : 0;
        }
    }
}

// ---------------------------------------------------------------------------
__global__ void __launch_bounds__(128) backtrack_k(
    const int* __restrict__ parents, const int* __restrict__ toks,
    int* __restrict__ out)
{
    const int tid = threadIdx.x;
    const int b = tid >> 2, kc = tid & 3;
    int ptr = kc;
    for (int t = 47; t >= 0; --t) {
        out[b * 192 + t * 4 + kc] = toks[t * 128 + b * 4 + ptr];
        ptr = parents[t * 128 + b * 4 + ptr];
    }
}

// ---------------------------------------------------------------------------
extern "C" void kernel_launch(void* const* d_in, const int* in_sizes, int n_in,
                              void* d_out, int out_size, void* d_ws, size_t ws_size,
                              hipStream_t stream)
{
    (void)in_sizes; (void)n_in; (void)out_size; (void)ws_size;
    const int* enc_in = (const int*)d_in[0];
    const float* enc_emb = (const float*)d_in[2];
    const float* dec_emb = (const float*)d_in[3];
    const float* W_enc = (const float*)d_in[4];
    const float* U_enc = (const float*)d_in[5];
    const float* b_enc = (const float*)d_in[6];
    const float* W_dec = (const float*)d_in[7];
    const float* U_dec = (const float*)d_in[8];
    const float* b_dec = (const float*)d_in[9];
    const float* W_mem = (const float*)d_in[10];
    const float* W_attn = (const float*)d_in[11];
    const float* W_out = (const float*)d_in[12];
    const float* b_out = (const float*)d_in[13];
    int* out = (int*)d_out;

    char* ws = (char*)d_ws;
    size_t off = 0;
    auto alloc = [&](size_t bytes) -> char* {
        char* p = ws + off;
        off = (off + bytes + 255) & ~(size_t)255;
        return p;
    };
    float* Xz       = (float*)alloc(128ull * 32 * 2048 * 4);
    float* enc_out  = (float*)alloc(32ull * 128 * 512 * 4);
    float* keysT    = (float*)alloc(32ull * 512 * 128 * 4);
    float* Bp       = (float*)alloc(1536ull * 2048 * 4);
    float* bp       = (float*)alloc(2048 * 4);
    float* enc_c    = (float*)alloc(32ull * 512 * 4);
    float* hzero    = (float*)alloc(512 * 4);
    float* ho0      = (float*)alloc(128ull * 512 * 4);
    float* ho1      = (float*)alloc(128ull * 512 * 4);
    float* c0       = (float*)alloc(128ull * 512 * 4);
    float* c1       = (float*)alloc(128ull * 512 * 4);
    float* at0      = (float*)alloc(128ull * 512 * 4);
    float* at1      = (float*)alloc(128ull * 512 * 4);
    float* pmax     = (float*)alloc(128ull * 512 * 4);
    float* psum     = (float*)alloc(128ull * 512 * 4);
    float* pval     = (float*)alloc(512ull * 512 * 4);
    int*   pcol     = (int*)alloc(512ull * 512 * 4);
    float* cum      = (float*)alloc(128 * 4);
    int* fin        = (int*)alloc(128 * 4);
    int* tok        = (int*)alloc(128 * 4);
    int* parc       = (int*)alloc(128 * 4);
    int* parents    = (int*)alloc(48 * 128 * 4);
    int* toks       = (int*)alloc(48 * 128 * 4);

    float* hoB[2] = {ho0, ho1};
    float* cB[2]  = {c0, c1};
    float* atB[2] = {at0, at1};

    pack_dec_k<<<(1536 * 2048) / 256, 256, 0, stream>>>(W_dec, U_dec, b_dec, Bp, bp,
                                                        enc_c, hzero);

    gemm_k<64, 64, 16, 2, 0><<<dim3(32, 64), 256, 0, stream>>>(
        enc_emb, W_enc, b_enc, Xz, 4096, 2048, 512, enc_in);

    for (int t = 0; t < 128; t++) {
        const float* hprev = t ? (enc_out + (size_t)(t - 1) * 512) : hzero;
        const long hstride = t ? (long)(128 * 512) : 0;
        enc_step_k<<<dim3(16, 16), 256, 0, stream>>>(
            Xz + (size_t)t * 32 * 2048, hprev, hstride, U_enc, enc_c,
            enc_out + (size_t)t * 512);
    }

    gemm_k<64, 64, 16, 0, 1><<<dim3(8, 64), 256, 0, stream>>>(
        enc_out, W_mem, nullptr, keysT, 4096, 512, 512, nullptr);

    init_dec_k<<<256, 256, 0, stream>>>(enc_out, enc_c, hoB[0], cB[0], atB[0],
                                        cum, fin, tok, parc);

    for (int t = 0; t < 48; t++) {
        const int p = t & 1;          // prev buffer index
        const int c = p ^ 1;          // cur buffer index
        zgemm_gates_k<<<dim3(32, 8), 256, 0, stream>>>(
            dec_emb, Bp, bp, tok, parc, atB[p], hoB[p], cB[p], cB[c], hoB[c]);
        attn_fused_k<<<128, 256, 0, stream>>>(
            hoB[c], keysT, enc_out, W_attn, atB[c]);
        logits_top_k<<<500, 256, 0, stream>>>(
            atB[c], W_out, b_out, pmax, psum, pval, pcol);
        merge_update_k<<<32, 1024, 0, stream>>>(
            pmax, psum, pval, pcol, cum, fin, tok, parc,
            parents + t * 128, toks + t * 128);
    }

    backtrack_k<<<1, 128, 0, stream>>>(parents, toks, out);
}